// Round 1
// baseline (28.356 us; speedup 1.0000x reference)
//
#include <hip/hip_runtime.h>
#include <math.h>

// Problem constants (match reference setup_inputs exactly)
constexpr int B  = 128;
constexpr int L  = 16384;
constexpr int D  = 512;
constexpr int H  = 32;
constexpr int NB = 8;
constexpr int IN = D + 5;   // 517
constexpr int BLK = 256;

__global__ __launch_bounds__(BLK) void pos_attn_kernel(
    const float* __restrict__ dec,        // (B,1,D)
    const float* __restrict__ mu_old,     // (B,1)
    const float* __restrict__ sigma_old,  // (B,1)
    const float* __restrict__ mc_old,     // (B,1)
    const float* __restrict__ ma_old,     // (B,1)
    const float* __restrict__ Wmu1, const float* __restrict__ bmu1,
    const float* __restrict__ Wmu2, const float* __restrict__ bmu2,
    const float* __restrict__ Wsg1, const float* __restrict__ bsg1,
    const float* __restrict__ Wsg2, const float* __restrict__ bsg2,
    const float* __restrict__ conf_temp, const float* __restrict__ conf_bias,
    const int*   __restrict__ src_len,    // (B,)
    const int*   __restrict__ step,       // scalar
    float* __restrict__ out)              // [B*L | B | B | B]
{
    const int b = blockIdx.x;
    const int t = threadIdx.x;

    __shared__ float x[IN];        // pos_in (517 floats)
    __shared__ float h[2 * H];     // relu hidden: [0..31]=mu net, [32..63]=sg net
    __shared__ float w8[2 * NB];   // layer-2 outputs
    __shared__ float bc[3];        // broadcast: mu, sigma, inv_denom
    __shared__ float red[BLK / 64];

    const int   slen = src_len[b];
    const float flen = (float)slen;

    // ---- stage pos_in into LDS ----
    for (int j = t; j < D; j += BLK) x[j] = dec[b * D + j];
    if (t == 0) {
        const int   st  = step[0];
        const float rc  = (float)(st + 1) / (float)L;   // rel_counter[step]
        const float rdc = rc * (float)L / flen;         // (rc*L)/lens
        x[D + 0] = mu_old[b];
        x[D + 1] = sigma_old[b] / flen;   // relative sigma
        x[D + 2] = mc_old[b];
        x[D + 3] = ma_old[b];
        x[D + 4] = rdc;
    }
    __syncthreads();

    // ---- layer 1: 64 dot products (2 nets x 32 hidden), length 517 each ----
    if (t < 2 * H) {
        const int net = t >> 5;        // 0 = mu, 1 = sigma
        const int k   = t & (H - 1);
        const float* __restrict__ W1 = net ? Wsg1 : Wmu1;
        const float* __restrict__ b1 = net ? bsg1 : bmu1;
        float a0 = 0.f, a1 = 0.f, a2 = 0.f, a3 = 0.f;
        int j = 0;
        for (; j + 3 < IN; j += 4) {
            a0 = fmaf(x[j + 0], W1[(j + 0) * H + k], a0);
            a1 = fmaf(x[j + 1], W1[(j + 1) * H + k], a1);
            a2 = fmaf(x[j + 2], W1[(j + 2) * H + k], a2);
            a3 = fmaf(x[j + 3], W1[(j + 3) * H + k], a3);
        }
        for (; j < IN; ++j) a0 = fmaf(x[j], W1[j * H + k], a0);
        const float acc = b1[k] + a0 + a1 + a2 + a3;
        h[t] = fmaxf(acc, 0.f);
    }
    __syncthreads();

    // ---- layer 2: 16 dot products of length 32 ----
    if (t < 2 * NB) {
        const int net = t >> 3;
        const int m   = t & (NB - 1);
        const float* __restrict__ W2 = net ? Wsg2 : Wmu2;
        const float* __restrict__ b2 = net ? bsg2 : bmu2;
        float acc = b2[m];
        for (int k = 0; k < H; ++k)
            acc = fmaf(h[net * H + k], W2[k * NB + m], acc);
        w8[t] = acc;
    }
    __syncthreads();

    // ---- combine with building blocks, write scalar outputs ----
    if (t == 0) {
        const float ss = 1.0f / flen;
        const float blocks[8] = { x[D + 0], x[D + 1], x[D + 2], x[D + 3], x[D + 4],
                                  ss, -ss, 1.0f };
        float mu = 0.f, sg = 0.f;
        for (int m = 0; m < 8; ++m) {
            mu += w8[m]      * blocks[m];
            sg += w8[NB + m] * blocks[m];
        }
        const float sigma = fmaxf(sg, 0.f) + 0.05f;   // MIN_SIGMA
        const float cb = conf_bias[0], ct = conf_temp[0];
        const float arg  = (-sigma + fmaxf(cb, 0.f)) / ct;
        const float conf = 1.0f / (1.0f + expf(-arg));
        out[(size_t)B * L + b]         = conf;
        out[(size_t)B * L + B + b]     = mu;
        out[(size_t)B * L + 2 * B + b] = sigma;
        bc[0] = mu;
        bc[1] = sigma;
    }
    __syncthreads();

    const float mu    = bc[0];
    const float sigma = bc[1];
    const float scale = (float)L / flen;       // L / lens (same op order as ref)
    const float invL  = 1.0f / (float)L;       // exact: 2^-14

    // ---- pass 1: masked gaussian, block-sum ----
    float lsum = 0.f;
    for (int i = t; i < L; i += BLK) {
        if (i < slen) {
            const float pos = ((float)(i + 1) * invL) * scale;
            const float d   = (pos - mu) / sigma;
            lsum += expf(-d * d);
        }
    }
    for (int off = 32; off > 0; off >>= 1)
        lsum += __shfl_down(lsum, off, 64);
    if ((t & 63) == 0) red[t >> 6] = lsum;
    __syncthreads();
    if (t == 0) {
        float tot = 0.f;
        for (int w = 0; w < BLK / 64; ++w) tot += red[w];
        bc[2] = 1.0f / fmaxf(tot, 1e-12f);
    }
    __syncthreads();
    const float inv = bc[2];

    // ---- pass 2: recompute + normalize + write (coalesced) ----
    for (int i = t; i < L; i += BLK) {
        float v = 0.f;
        if (i < slen) {
            const float pos = ((float)(i + 1) * invL) * scale;
            const float d   = (pos - mu) / sigma;
            v = expf(-d * d) * inv;
        }
        out[(size_t)b * L + i] = v;
    }
}

extern "C" void kernel_launch(void* const* d_in, const int* in_sizes, int n_in,
                              void* d_out, int out_size, void* d_ws, size_t ws_size,
                              hipStream_t stream) {
    const float* dec   = (const float*)d_in[0];
    // d_in[1] = encoder_outputs: unused by the reference
    const float* mu_o  = (const float*)d_in[2];
    const float* sg_o  = (const float*)d_in[3];
    const float* mc_o  = (const float*)d_in[4];
    const float* ma_o  = (const float*)d_in[5];
    const float* Wmu1  = (const float*)d_in[6];
    const float* bmu1  = (const float*)d_in[7];
    const float* Wmu2  = (const float*)d_in[8];
    const float* bmu2  = (const float*)d_in[9];
    const float* Wsg1  = (const float*)d_in[10];
    const float* bsg1  = (const float*)d_in[11];
    const float* Wsg2  = (const float*)d_in[12];
    const float* bsg2  = (const float*)d_in[13];
    const float* ctmp  = (const float*)d_in[14];
    const float* cbias = (const float*)d_in[15];
    const int*   slen  = (const int*)d_in[16];
    const int*   stp   = (const int*)d_in[17];

    pos_attn_kernel<<<B, BLK, 0, stream>>>(
        dec, mu_o, sg_o, mc_o, ma_o,
        Wmu1, bmu1, Wmu2, bmu2, Wsg1, bsg1, Wsg2, bsg2,
        ctmp, cbias, slen, stp, (float*)d_out);
}

// Round 2
// 25.500 us; speedup vs baseline: 1.1120x; 1.1120x over previous
//
#include <hip/hip_runtime.h>
#include <math.h>

// Problem constants (match reference setup_inputs exactly)
constexpr int B  = 128;
constexpr int L  = 16384;
constexpr int D  = 512;
constexpr int H  = 32;
constexpr int NB = 8;
constexpr int IN = D + 5;   // 517

constexpr int S     = 16;        // chunks per batch
constexpr int CHUNK = L / S;     // 1024 elements per block
constexpr int BLK2  = 256;       // CHUNK = BLK2 * 4 (one float4 iter/thread)

// d_ws layout (floats): [0..B) mu, [B..2B) sigma, [2B..3B) sum

// ---------------- K1: per-batch MLP -> mu/sigma/conf, zero sums ----------------
__global__ __launch_bounds__(64) void k1_mlp(
    const float* __restrict__ dec,
    const float* __restrict__ mu_old, const float* __restrict__ sigma_old,
    const float* __restrict__ mc_old, const float* __restrict__ ma_old,
    const float* __restrict__ Wmu1, const float* __restrict__ bmu1,
    const float* __restrict__ Wmu2, const float* __restrict__ bmu2,
    const float* __restrict__ Wsg1, const float* __restrict__ bsg1,
    const float* __restrict__ Wsg2, const float* __restrict__ bsg2,
    const float* __restrict__ conf_temp, const float* __restrict__ conf_bias,
    const int* __restrict__ src_len, const int* __restrict__ step,
    float* __restrict__ out, float* __restrict__ ws)
{
    const int b = blockIdx.x;
    const int t = threadIdx.x;

    __shared__ float x[IN];
    __shared__ float h[2 * H];
    __shared__ float w8[2 * NB];

    const float flen = (float)src_len[b];

    // stage pos_in
    for (int j = t; j < D; j += 64) x[j] = dec[b * D + j];
    if (t == 0) {
        const int   st  = step[0];
        const float rc  = (float)(st + 1) / (float)L;
        x[D + 0] = mu_old[b];
        x[D + 1] = sigma_old[b] / flen;
        x[D + 2] = mc_old[b];
        x[D + 3] = ma_old[b];
        x[D + 4] = rc * (float)L / flen;
    }
    __syncthreads();

    // layer 1: 64 dots (2 nets x 32 hidden) of length 517
    {
        const int net = t >> 5;
        const int k   = t & (H - 1);
        const float* __restrict__ W1 = net ? Wsg1 : Wmu1;
        const float* __restrict__ b1 = net ? bsg1 : bmu1;
        float a0 = 0.f, a1 = 0.f, a2 = 0.f, a3 = 0.f;
        int j = 0;
        for (; j + 3 < IN; j += 4) {
            a0 = fmaf(x[j + 0], W1[(j + 0) * H + k], a0);
            a1 = fmaf(x[j + 1], W1[(j + 1) * H + k], a1);
            a2 = fmaf(x[j + 2], W1[(j + 2) * H + k], a2);
            a3 = fmaf(x[j + 3], W1[(j + 3) * H + k], a3);
        }
        for (; j < IN; ++j) a0 = fmaf(x[j], W1[j * H + k], a0);
        h[t] = fmaxf(b1[k] + a0 + a1 + a2 + a3, 0.f);
    }
    __syncthreads();

    // layer 2: 16 dots of length 32
    if (t < 2 * NB) {
        const int net = t >> 3;
        const int m   = t & (NB - 1);
        const float* __restrict__ W2 = net ? Wsg2 : Wmu2;
        const float* __restrict__ b2 = net ? bsg2 : bmu2;
        float acc = b2[m];
        for (int k = 0; k < H; ++k)
            acc = fmaf(h[net * H + k], W2[k * NB + m], acc);
        w8[t] = acc;
    }
    __syncthreads();

    if (t == 0) {
        const float ss = 1.0f / flen;
        const float blocks[8] = { x[D + 0], x[D + 1], x[D + 2], x[D + 3], x[D + 4],
                                  ss, -ss, 1.0f };
        float mu = 0.f, sg = 0.f;
        for (int m = 0; m < 8; ++m) {
            mu += w8[m]      * blocks[m];
            sg += w8[NB + m] * blocks[m];
        }
        const float sigma = fmaxf(sg, 0.f) + 0.05f;
        const float arg   = (-sigma + fmaxf(conf_bias[0], 0.f)) / conf_temp[0];
        const float conf  = 1.0f / (1.0f + __expf(-arg));
        out[(size_t)B * L + b]         = conf;
        out[(size_t)B * L + B + b]     = mu;
        out[(size_t)B * L + 2 * B + b] = sigma;
        ws[b]         = mu;
        ws[B + b]     = sigma;
        ws[2 * B + b] = 0.0f;   // zero the sum slot (ws is NOT re-poisoned; we own init)
    }
}

// ---------------- K2: partial Gaussian sums ----------------
__global__ __launch_bounds__(BLK2) void k2_sum(
    const int* __restrict__ src_len, const float* __restrict__ ws_in,
    float* __restrict__ sums)
{
    const int b = blockIdx.x / S;
    const int c = blockIdx.x % S;
    const int t = threadIdx.x;

    const int   slen  = src_len[b];
    const float flen  = (float)slen;
    const float mu    = ws_in[b];
    const float sigma = ws_in[B + b];
    const float scale = (float)L / flen;
    const float invL  = 1.0f / (float)L;
    const float isg   = 1.0f / sigma;

    const int i0 = c * CHUNK + t * 4;   // element index within batch row
    float lsum = 0.f;
    #pragma unroll
    for (int u = 0; u < 4; ++u) {
        const int i = i0 + u;
        if (i < slen) {
            const float pos = ((float)(i + 1) * invL) * scale;
            const float d   = (pos - mu) * isg;
            lsum += __expf(-d * d);
        }
    }
    // wave64 reduce
    for (int off = 32; off > 0; off >>= 1)
        lsum += __shfl_down(lsum, off, 64);
    __shared__ float red[BLK2 / 64];
    if ((t & 63) == 0) red[t >> 6] = lsum;
    __syncthreads();
    if (t == 0) {
        float tot = red[0];
        for (int w = 1; w < BLK2 / 64; ++w) tot += red[w];
        atomicAdd(&sums[b], tot);
    }
}

// ---------------- K3: normalize + write ----------------
__global__ __launch_bounds__(BLK2) void k3_write(
    const int* __restrict__ src_len, const float* __restrict__ ws_in,
    float* __restrict__ out)
{
    const int b = blockIdx.x / S;
    const int c = blockIdx.x % S;
    const int t = threadIdx.x;

    const int   slen  = src_len[b];
    const float flen  = (float)slen;
    const float mu    = ws_in[b];
    const float sigma = ws_in[B + b];
    const float inv   = 1.0f / fmaxf(ws_in[2 * B + b], 1e-12f);
    const float scale = (float)L / flen;
    const float invL  = 1.0f / (float)L;
    const float isg   = 1.0f / sigma;

    const int i0 = c * CHUNK + t * 4;
    float4 v;
    float* vv = (float*)&v;
    #pragma unroll
    for (int u = 0; u < 4; ++u) {
        const int i = i0 + u;
        float z = 0.f;
        if (i < slen) {
            const float pos = ((float)(i + 1) * invL) * scale;
            const float d   = (pos - mu) * isg;
            z = __expf(-d * d) * inv;
        }
        vv[u] = z;
    }
    *(float4*)&out[(size_t)b * L + i0] = v;
}

extern "C" void kernel_launch(void* const* d_in, const int* in_sizes, int n_in,
                              void* d_out, int out_size, void* d_ws, size_t ws_size,
                              hipStream_t stream) {
    const float* dec   = (const float*)d_in[0];
    // d_in[1] = encoder_outputs: unused by the reference
    const float* mu_o  = (const float*)d_in[2];
    const float* sg_o  = (const float*)d_in[3];
    const float* mc_o  = (const float*)d_in[4];
    const float* ma_o  = (const float*)d_in[5];
    const float* Wmu1  = (const float*)d_in[6];
    const float* bmu1  = (const float*)d_in[7];
    const float* Wmu2  = (const float*)d_in[8];
    const float* bmu2  = (const float*)d_in[9];
    const float* Wsg1  = (const float*)d_in[10];
    const float* bsg1  = (const float*)d_in[11];
    const float* Wsg2  = (const float*)d_in[12];
    const float* bsg2  = (const float*)d_in[13];
    const float* ctmp  = (const float*)d_in[14];
    const float* cbias = (const float*)d_in[15];
    const int*   slen  = (const int*)d_in[16];
    const int*   stp   = (const int*)d_in[17];

    float* ws  = (float*)d_ws;
    float* out = (float*)d_out;

    k1_mlp<<<B, 64, 0, stream>>>(dec, mu_o, sg_o, mc_o, ma_o,
                                 Wmu1, bmu1, Wmu2, bmu2,
                                 Wsg1, bsg1, Wsg2, bsg2,
                                 ctmp, cbias, slen, stp, out, ws);
    k2_sum<<<B * S, BLK2, 0, stream>>>(slen, ws, ws + 2 * B);
    k3_write<<<B * S, BLK2, 0, stream>>>(slen, ws, out);
}

// Round 3
// 18.628 us; speedup vs baseline: 1.5222x; 1.3689x over previous
//
#include <hip/hip_runtime.h>
#include <math.h>

// Problem constants (match reference setup_inputs exactly)
constexpr int B  = 128;
constexpr int L  = 16384;
constexpr int D  = 512;
constexpr int H  = 32;
constexpr int NB = 8;
constexpr int IN = D + 5;   // 517

constexpr int S     = 4;         // chunks per batch row (K2 blocks per batch)
constexpr int CHUNK = L / S;     // 4096 elements per block
constexpr int BLK   = 256;

// d_ws layout (floats): [0..B) mu, [B..2B) sigma

// ---------------- K1: per-batch MLP -> mu/sigma/conf ----------------
__global__ __launch_bounds__(BLK) void k1_mlp(
    const float* __restrict__ dec,
    const float* __restrict__ mu_old, const float* __restrict__ sigma_old,
    const float* __restrict__ mc_old, const float* __restrict__ ma_old,
    const float* __restrict__ Wmu1, const float* __restrict__ bmu1,
    const float* __restrict__ Wmu2, const float* __restrict__ bmu2,
    const float* __restrict__ Wsg1, const float* __restrict__ bsg1,
    const float* __restrict__ Wsg2, const float* __restrict__ bsg2,
    const float* __restrict__ conf_temp, const float* __restrict__ conf_bias,
    const int* __restrict__ src_len, const int* __restrict__ step,
    float* __restrict__ out, float* __restrict__ ws)
{
    const int b = blockIdx.x;
    const int t = threadIdx.x;

    __shared__ float x[IN];
    __shared__ float part[4][64];   // layer-1 slice partials
    __shared__ float h[2 * H];
    __shared__ float w8[2 * NB];

    const float flen = (float)src_len[b];

    // stage pos_in (512 floats as 128 float4, + 5 tail scalars)
    if (t < 128) ((float4*)x)[t] = ((const float4*)(dec + (size_t)b * D))[t];
    if (t == 0) {
        const int st = step[0];
        x[D + 0] = mu_old[b];
        x[D + 1] = sigma_old[b] / flen;
        x[D + 2] = mc_old[b];
        x[D + 3] = ma_old[b];
        x[D + 4] = ((float)(st + 1) / (float)L) * (float)L / flen;
    }
    __syncthreads();

    // ---- layer 1: 64 dots (2 nets x 32 hidden), each split over 4 threads ----
    {
        const int s   = t >> 6;        // slice 0..3
        const int d   = t & 63;        // dot 0..63
        const int net = d >> 5;
        const int k   = d & (H - 1);
        const float* __restrict__ W1 = net ? Wsg1 : Wmu1;
        const int j0 = (s == 0) ? 0 : (1 + s * 129);
        const int j1 = j0 + ((s == 0) ? 130 : 129);
        float a0 = 0.f, a1 = 0.f, a2 = 0.f, a3 = 0.f;
        int j = j0;
        for (; j + 3 < j1; j += 4) {
            a0 = fmaf(x[j + 0], W1[(j + 0) * H + k], a0);
            a1 = fmaf(x[j + 1], W1[(j + 1) * H + k], a1);
            a2 = fmaf(x[j + 2], W1[(j + 2) * H + k], a2);
            a3 = fmaf(x[j + 3], W1[(j + 3) * H + k], a3);
        }
        for (; j < j1; ++j) a0 = fmaf(x[j], W1[j * H + k], a0);
        part[s][d] = a0 + a1 + a2 + a3;
    }
    __syncthreads();

    if (t < 64) {
        const int net = t >> 5;
        const int k   = t & (H - 1);
        const float* __restrict__ b1 = net ? bsg1 : bmu1;
        h[t] = fmaxf(b1[k] + part[0][t] + part[1][t] + part[2][t] + part[3][t], 0.f);
    }
    __syncthreads();

    // ---- layer 2: 16 dots of length 32 ----
    if (t < 2 * NB) {
        const int net = t >> 3;
        const int m   = t & (NB - 1);
        const float* __restrict__ W2 = net ? Wsg2 : Wmu2;
        const float* __restrict__ b2 = net ? bsg2 : bmu2;
        float acc = b2[m];
        for (int k = 0; k < H; ++k)
            acc = fmaf(h[net * H + k], W2[k * NB + m], acc);
        w8[t] = acc;
    }
    __syncthreads();

    if (t == 0) {
        const float ss = 1.0f / flen;
        const float blocks[8] = { x[D + 0], x[D + 1], x[D + 2], x[D + 3], x[D + 4],
                                  ss, -ss, 1.0f };
        float mu = 0.f, sg = 0.f;
        for (int m = 0; m < 8; ++m) {
            mu += w8[m]      * blocks[m];
            sg += w8[NB + m] * blocks[m];
        }
        const float sigma = fmaxf(sg, 0.f) + 0.05f;
        const float arg   = (-sigma + fmaxf(conf_bias[0], 0.f)) / conf_temp[0];
        const float conf  = 1.0f / (1.0f + __expf(-arg));
        out[(size_t)B * L + b]         = conf;
        out[(size_t)B * L + B + b]     = mu;
        out[(size_t)B * L + 2 * B + b] = sigma;
        ws[b]     = mu;      // fresh every call — no cross-call state
        ws[B + b] = sigma;
    }
}

// ---------------- K2: redundant full-row sum + normalize + write ----------------
// Each block handles chunk c of batch b, but sums the WHOLE row (cheap) so no
// cross-block reduction / extra dispatch is needed. Own-chunk z's stay in regs.
__global__ __launch_bounds__(BLK) void k2_fused(
    const int* __restrict__ src_len, const float* __restrict__ ws_in,
    float* __restrict__ out)
{
    const int b = blockIdx.x >> 2;        // / S
    const int c = blockIdx.x & (S - 1);
    const int t = threadIdx.x;

    const int   slen  = src_len[b];
    const float flen  = (float)slen;
    const float mu    = ws_in[b];
    const float sigma = ws_in[B + b];
    const float scale = (float)L / flen;
    const float invL  = 1.0f / (float)L;   // exact 2^-14
    const float isg   = 1.0f / sigma;

    float4 v[4];                 // own chunk: 4 coalesced float4 per thread
    float  lsum = 0.f;

    #pragma unroll
    for (int g = 0; g < S; ++g) {
        #pragma unroll
        for (int u = 0; u < 4; ++u) {
            const int base = g * CHUNK + u * (BLK * 4) + t * 4;
            float z0, z1, z2, z3;
            #pragma unroll
            for (int e = 0; e < 4; ++e) {
                const int i = base + e;
                float z = 0.f;
                if (i < slen) {
                    const float pos = ((float)(i + 1) * invL) * scale;
                    const float dd  = (pos - mu) * isg;
                    z = __expf(-dd * dd);
                }
                lsum += z;
                if (e == 0) z0 = z; else if (e == 1) z1 = z;
                else if (e == 2) z2 = z; else z3 = z;
            }
            if (g == c) v[u] = make_float4(z0, z1, z2, z3);
        }
    }

    // block reduction of lsum (256 threads = 4 waves)
    for (int off = 32; off > 0; off >>= 1)
        lsum += __shfl_down(lsum, off, 64);
    __shared__ float red[4];
    __shared__ float binv;
    if ((t & 63) == 0) red[t >> 6] = lsum;
    __syncthreads();
    if (t == 0) binv = 1.0f / fmaxf(red[0] + red[1] + red[2] + red[3], 1e-12f);
    __syncthreads();
    const float inv = binv;

    float4* o = (float4*)(out + (size_t)b * L + c * CHUNK);
    #pragma unroll
    for (int u = 0; u < 4; ++u) {
        float4 w = v[u];
        w.x *= inv; w.y *= inv; w.z *= inv; w.w *= inv;
        o[u * BLK + t] = w;      // lane-contiguous 16B stores -> 1KB/wave
    }
}

extern "C" void kernel_launch(void* const* d_in, const int* in_sizes, int n_in,
                              void* d_out, int out_size, void* d_ws, size_t ws_size,
                              hipStream_t stream) {
    const float* dec   = (const float*)d_in[0];
    // d_in[1] = encoder_outputs: unused by the reference
    const float* mu_o  = (const float*)d_in[2];
    const float* sg_o  = (const float*)d_in[3];
    const float* mc_o  = (const float*)d_in[4];
    const float* ma_o  = (const float*)d_in[5];
    const float* Wmu1  = (const float*)d_in[6];
    const float* bmu1  = (const float*)d_in[7];
    const float* Wmu2  = (const float*)d_in[8];
    const float* bmu2  = (const float*)d_in[9];
    const float* Wsg1  = (const float*)d_in[10];
    const float* bsg1  = (const float*)d_in[11];
    const float* Wsg2  = (const float*)d_in[12];
    const float* bsg2  = (const float*)d_in[13];
    const float* ctmp  = (const float*)d_in[14];
    const float* cbias = (const float*)d_in[15];
    const int*   slen  = (const int*)d_in[16];
    const int*   stp   = (const int*)d_in[17];

    float* ws  = (float*)d_ws;
    float* out = (float*)d_out;

    k1_mlp<<<B, BLK, 0, stream>>>(dec, mu_o, sg_o, mc_o, ma_o,
                                  Wmu1, bmu1, Wmu2, bmu2,
                                  Wsg1, bsg1, Wsg2, bsg2,
                                  ctmp, cbias, slen, stp, out, ws);
    k2_fused<<<B * S, BLK, 0, stream>>>(slen, ws, out);
}

// Round 4
// 12.379 us; speedup vs baseline: 2.2906x; 1.5048x over previous
//
#include <hip/hip_runtime.h>
#include <math.h>

// Problem constants (match reference setup_inputs exactly)
constexpr int B  = 128;
constexpr int L  = 16384;
constexpr int D  = 512;
constexpr int H  = 32;
constexpr int NB = 8;
constexpr int IN = D + 5;   // 517

constexpr int BLKX  = 1024;      // 16 waves per block
constexpr int S     = 2;         // blocks per batch row
constexpr int CHUNK = L / S;     // 8192 elements (2048 float4) per block

// Single fused kernel: each block redundantly computes its batch's MLP and the
// full row-sum (both cheap), keeps its own half-row in registers, normalizes,
// writes. One dispatch total -> minimal replay overhead.
__global__ __launch_bounds__(BLKX) void pos_attn_fused(
    const float* __restrict__ dec,
    const float* __restrict__ mu_old, const float* __restrict__ sigma_old,
    const float* __restrict__ mc_old, const float* __restrict__ ma_old,
    const float* __restrict__ Wmu1, const float* __restrict__ bmu1,
    const float* __restrict__ Wmu2, const float* __restrict__ bmu2,
    const float* __restrict__ Wsg1, const float* __restrict__ bsg1,
    const float* __restrict__ Wsg2, const float* __restrict__ bsg2,
    const float* __restrict__ conf_temp, const float* __restrict__ conf_bias,
    const int* __restrict__ src_len, const int* __restrict__ step,
    float* __restrict__ out)
{
    const int b = blockIdx.x >> 1;        // batch
    const int c = blockIdx.x & (S - 1);   // half-row chunk
    const int t = threadIdx.x;

    __shared__ float x[IN];
    __shared__ float part[16][64];   // layer-1 slice partials
    __shared__ float h[2 * H];
    __shared__ float w8[2 * NB];
    __shared__ float red[BLKX / 64];
    __shared__ float bcast[3];       // mu, sigma, inv_denom

    const int   slen = src_len[b];
    const float flen = (float)slen;

    // ---- stage pos_in (512 floats as 128 float4 + 5 tail scalars) ----
    if (t < 128) ((float4*)x)[t] = ((const float4*)(dec + (size_t)b * D))[t];
    if (t == 0) {
        const int st = step[0];
        x[D + 0] = mu_old[b];
        x[D + 1] = sigma_old[b] / flen;
        x[D + 2] = mc_old[b];
        x[D + 3] = ma_old[b];
        x[D + 4] = ((float)(st + 1) / (float)L) * (float)L / flen;
    }
    __syncthreads();

    // ---- layer 1: 64 dots (2 nets x 32 hidden), each split over 16 threads ----
    {
        const int s   = t >> 6;        // slice 0..15
        const int d   = t & 63;        // dot 0..63
        const int net = d >> 5;
        const int k   = d & (H - 1);
        const float* __restrict__ W1 = net ? Wsg1 : Wmu1;
        const int j0 = (s == 0) ? 0  : (37 + (s - 1) * 32);   // slice 0: 37, rest: 32
        const int j1 = (s == 0) ? 37 : (j0 + 32);
        float a0 = 0.f, a1 = 0.f, a2 = 0.f, a3 = 0.f;
        int j = j0;
        for (; j + 3 < j1; j += 4) {
            a0 = fmaf(x[j + 0], W1[(j + 0) * H + k], a0);
            a1 = fmaf(x[j + 1], W1[(j + 1) * H + k], a1);
            a2 = fmaf(x[j + 2], W1[(j + 2) * H + k], a2);
            a3 = fmaf(x[j + 3], W1[(j + 3) * H + k], a3);
        }
        for (; j < j1; ++j) a0 = fmaf(x[j], W1[j * H + k], a0);
        part[s][d] = a0 + a1 + a2 + a3;
    }
    __syncthreads();

    if (t < 64) {
        const int net = t >> 5;
        const int k   = t & (H - 1);
        const float* __restrict__ b1 = net ? bsg1 : bmu1;
        float acc = b1[k];
        #pragma unroll
        for (int s = 0; s < 16; ++s) acc += part[s][t];
        h[t] = fmaxf(acc, 0.f);
    }
    __syncthreads();

    // ---- layer 2: 16 dots of length 32 ----
    if (t < 2 * NB) {
        const int net = t >> 3;
        const int m   = t & (NB - 1);
        const float* __restrict__ W2 = net ? Wsg2 : Wmu2;
        const float* __restrict__ b2 = net ? bsg2 : bmu2;
        float acc = b2[m];
        for (int k = 0; k < H; ++k)
            acc = fmaf(h[net * H + k], W2[k * NB + m], acc);
        w8[t] = acc;
    }
    __syncthreads();

    if (t == 0) {
        const float ss = 1.0f / flen;
        const float blocks[8] = { x[D + 0], x[D + 1], x[D + 2], x[D + 3], x[D + 4],
                                  ss, -ss, 1.0f };
        float mu = 0.f, sg = 0.f;
        for (int m = 0; m < 8; ++m) {
            mu += w8[m]      * blocks[m];
            sg += w8[NB + m] * blocks[m];
        }
        const float sigma = fmaxf(sg, 0.f) + 0.05f;
        if (c == 0) {   // one block per batch writes the scalar outputs
            const float arg  = (-sigma + fmaxf(conf_bias[0], 0.f)) / conf_temp[0];
            const float conf = 1.0f / (1.0f + __expf(-arg));
            out[(size_t)B * L + b]         = conf;
            out[(size_t)B * L + B + b]     = mu;
            out[(size_t)B * L + 2 * B + b] = sigma;
        }
        bcast[0] = mu;
        bcast[1] = sigma;
    }
    __syncthreads();

    const float mu    = bcast[0];
    const float sigma = bcast[1];
    const float scale = (float)L / flen;
    const float invL  = 1.0f / (float)L;   // exact 2^-14
    const float isg   = 1.0f / sigma;

    // ---- full-row gaussian sum (redundant per block); own half kept in regs ----
    float4 v[2];
    float  lsum = 0.f;
    #pragma unroll
    for (int g = 0; g < 4; ++g) {          // 4 groups x 1024 threads x float4 = L
        const int base = (g * BLKX + t) * 4;
        float z[4];
        #pragma unroll
        for (int e = 0; e < 4; ++e) {
            const int i = base + e;
            float zz = 0.f;
            if (i < slen) {
                const float pos = ((float)(i + 1) * invL) * scale;
                const float dd  = (pos - mu) * isg;
                zz = __expf(-dd * dd);
            }
            lsum += zz;
            z[e] = zz;
        }
        if ((g >> 1) == c) v[g & 1] = make_float4(z[0], z[1], z[2], z[3]);
    }

    // block reduction over 16 waves
    for (int off = 32; off > 0; off >>= 1)
        lsum += __shfl_down(lsum, off, 64);
    if ((t & 63) == 0) red[t >> 6] = lsum;
    __syncthreads();
    if (t == 0) {
        float tot = 0.f;
        for (int w = 0; w < BLKX / 64; ++w) tot += red[w];
        bcast[2] = 1.0f / fmaxf(tot, 1e-12f);
    }
    __syncthreads();
    const float inv = bcast[2];

    // ---- normalize + write own chunk (coalesced float4) ----
    float4* o = (float4*)(out + (size_t)b * L + c * CHUNK);
    #pragma unroll
    for (int u = 0; u < 2; ++u) {
        float4 w = v[u];
        w.x *= inv; w.y *= inv; w.z *= inv; w.w *= inv;
        o[u * BLKX + t] = w;
    }
}

extern "C" void kernel_launch(void* const* d_in, const int* in_sizes, int n_in,
                              void* d_out, int out_size, void* d_ws, size_t ws_size,
                              hipStream_t stream) {
    const float* dec   = (const float*)d_in[0];
    // d_in[1] = encoder_outputs: unused by the reference
    const float* mu_o  = (const float*)d_in[2];
    const float* sg_o  = (const float*)d_in[3];
    const float* mc_o  = (const float*)d_in[4];
    const float* ma_o  = (const float*)d_in[5];
    const float* Wmu1  = (const float*)d_in[6];
    const float* bmu1  = (const float*)d_in[7];
    const float* Wmu2  = (const float*)d_in[8];
    const float* bmu2  = (const float*)d_in[9];
    const float* Wsg1  = (const float*)d_in[10];
    const float* bsg1  = (const float*)d_in[11];
    const float* Wsg2  = (const float*)d_in[12];
    const float* bsg2  = (const float*)d_in[13];
    const float* ctmp  = (const float*)d_in[14];
    const float* cbias = (const float*)d_in[15];
    const int*   slen  = (const int*)d_in[16];
    const int*   stp   = (const int*)d_in[17];

    pos_attn_fused<<<B * S, BLKX, 0, stream>>>(
        dec, mu_o, sg_o, mc_o, ma_o,
        Wmu1, bmu1, Wmu2, bmu2, Wsg1, bsg1, Wsg2, bsg2,
        ctmp, cbias, slen, stp, (float*)d_out);
}